// Round 17
// baseline (535.371 us; speedup 1.0000x reference)
//
#include <hip/hip_runtime.h>
#include <hip/hip_bf16.h>
#include <stdint.h>

#define BB 8
#define CC 64
#define HH 256
#define WW 256
#define NPIX 65536
#define HEADS 4
#define HD 16
#define PRS 76    // pr_s row stride in shorts (conflict-free b128, verified r6)
#define QKS 268   // qk_s px stride in shorts (same residue-6 dword class as PRS)
#define KOFF (64 * QKS)

using bf16 = __hip_bfloat16;
typedef __attribute__((ext_vector_type(8))) short short8;
typedef __attribute__((ext_vector_type(4))) float f32x4;
typedef __attribute__((ext_vector_type(2))) float f32x2;

__device__ __forceinline__ float bf2f(bf16 v) { return __bfloat162float(v); }
__device__ __forceinline__ bf16 f2bf(float v) { return __float2bfloat16(v); }
__device__ __forceinline__ short f2bfs(float f) { bf16 h = __float2bfloat16(f); return *reinterpret_cast<short*>(&h); }
__device__ __forceinline__ float bfs2f(short s) { return __uint_as_float(((uint32_t)(uint16_t)s) << 16); }
__device__ __forceinline__ uint32_t pk2(float a, float b) {
  return (uint32_t)(uint16_t)f2bfs(a) | ((uint32_t)(uint16_t)f2bfs(b) << 16);
}
__device__ __forceinline__ uint32_t pk2t(float a, float b) {
  return (__float_as_uint(a) >> 16) | (__float_as_uint(b) & 0xffff0000u);
}
__device__ __forceinline__ short8 zero8() { short8 z = {0, 0, 0, 0, 0, 0, 0, 0}; return z; }
__device__ __forceinline__ f32x2 unpk2(uint32_t w) {
  f32x2 r;
  r.x = __uint_as_float(w << 16);
  r.y = __uint_as_float(w & 0xffff0000u);
  return r;
}

// ---------------- prep: wcpb = w_comp*w_proj folded (bf16); wqkvb, wcb = bf16 weights
__global__ void k_prep(const float* __restrict__ w_comp, const float* __restrict__ w_proj,
                       const float* __restrict__ w_q, const float* __restrict__ w_k,
                       const float* __restrict__ w_v,
                       short* __restrict__ wcpb, short* __restrict__ wqkvb,
                       short* __restrict__ wcb) {
  int idx = blockIdx.x * 256 + threadIdx.x;
  if (idx < 9 * 16 * 64) {
    int c = idx & 63;
    int o = (idx >> 6) & 15;
    int kk = idx >> 10;
    float acc = 0.f;
    for (int m = 0; m < 64; ++m)
      acc += w_comp[o * 64 + m] * w_proj[(m * 64 + c) * 9 + kk];
    wcpb[idx] = f2bfs(acc);
  }
  if (idx < 3 * 4096) {
    const float* Ws[3] = {w_q, w_k, w_v};
    wqkvb[idx] = f2bfs(Ws[idx >> 12][idx & 4095]);
  }
  if (idx < 1024) wcb[idx] = f2bfs(w_comp[idx]);
}

// ---------------- LayerNorm: x (channel-major fp32) -> xn (pixel-major bf16)
__global__ __launch_bounds__(256)
void k_ln(const float* __restrict__ x, const float* __restrict__ ln_w,
          const float* __restrict__ ln_b, short* __restrict__ xnb) {
  const int tid = threadIdx.x;
  const int b = blockIdx.x >> 8;
  const int n = ((blockIdx.x & 255) << 8) + tid;
  const float* xp = x + (size_t)b * CC * NPIX + n;
  float v[64];
  float s = 0.f, s2 = 0.f;
#pragma unroll
  for (int c = 0; c < 64; ++c) {
    float t0 = xp[(size_t)c * NPIX];
    v[c] = t0; s += t0; s2 += t0 * t0;
  }
  const float mu = s * (1.f / 64.f);
  const float r = rsqrtf(s2 * (1.f / 64.f) - mu * mu + 1e-6f);
  short* op = xnb + ((size_t)b * NPIX + n) * 64;
#pragma unroll
  for (int c8 = 0; c8 < 8; ++c8) {
    uint32_t pk[4];
#pragma unroll
    for (int j = 0; j < 4; ++j) {
      const int c0 = c8 * 8 + 2 * j;
      float f0 = (v[c0] - mu) * r * ln_w[c0] + ln_b[c0];
      float f1 = (v[c0 + 1] - mu) * r * ln_w[c0 + 1] + ln_b[c0 + 1];
      pk[j] = pk2(f0, f1);
    }
    *reinterpret_cast<uint4*>(op + c8 * 8) = make_uint4(pk[0], pk[1], pk[2], pk[3]);
  }
}

// ---- one q-or-k pass: 1x1 MFMA -> pr_s -> depthwise -> packed regs + sumsq
template <int T>
__device__ __forceinline__ void qk_phase(
    const short* __restrict__ xnb, const short* __restrict__ wqkvb,
    const float* __restrict__ dmt, short* pr_s, int b, int x0, int y0,
    int lane, int wv, int olocal, int g,
    uint32_t (&opk)[16], float (&osq)[8]) {
  short8 Bt[4][2];
#pragma unroll
  for (int ot = 0; ot < 4; ++ot) {
    const short* wb = wqkvb + T * 4096 + (ot * 16 + olocal) * 64 + g * 8;
    Bt[ot][0] = *reinterpret_cast<const short8*>(wb);
    Bt[ot][1] = *reinterpret_cast<const short8*>(wb + 32);
  }
  short8 a0[3], a1[3];
#pragma unroll
  for (int j = 0; j < 3; ++j) {
    const int pt = wv + j * 8;
    const int p = pt * 16 + olocal;
    const int py = y0 + p / 18;
    const int px_ = x0 + p % 18;
    const bool vld = (pt < 21) && (p < 324) && ((unsigned)py < 256u) && ((unsigned)px_ < 256u);
    if (vld) {
      const short* ab = xnb + ((size_t)b * NPIX + py * WW + px_) * 64 + g * 8;
      a0[j] = *reinterpret_cast<const short8*>(ab);
      a1[j] = *reinterpret_cast<const short8*>(ab + 32);
    } else {
      a0[j] = zero8();
      a1[j] = zero8();
    }
  }
#pragma unroll
  for (int j = 0; j < 3; ++j) {
    const int pt = wv + j * 8;
    if (pt >= 21) continue;
    const int p2 = pt * 16 + olocal;
#pragma unroll
    for (int ot = 0; ot < 4; ++ot) {
      f32x4 acc = {0.f, 0.f, 0.f, 0.f};
      acc = __builtin_amdgcn_mfma_f32_16x16x32_bf16(Bt[ot][0], a0[j], acc, 0, 0, 0);
      acc = __builtin_amdgcn_mfma_f32_16x16x32_bf16(Bt[ot][1], a1[j], acc, 0, 0, 0);
      uint2 st;
      st.x = pk2t(acc[0], acc[1]);
      st.y = pk2t(acc[2], acc[3]);
      *reinterpret_cast<uint2*>(&pr_s[p2 * PRS + ot * 16 + g * 4]) = st;
    }
  }
  __syncthreads();
  f32x2 dm2[9][4];
#pragma unroll
  for (int u2 = 0; u2 < 4; ++u2)
#pragma unroll
    for (int kk = 0; kk < 9; ++kk) {
      dm2[kk][u2].x = dmt[(wv * 8 + 2 * u2) * 9 + kk];
      dm2[kk][u2].y = dmt[(wv * 8 + 2 * u2 + 1) * 9 + kk];
    }
#pragma unroll
  for (int i = 0; i < 4; ++i) {
    const int pxl = lane + i * 64;
    const int oy = pxl >> 4, ox = pxl & 15;
    uint4 pw[9];
#pragma unroll
    for (int ky = 0; ky < 3; ++ky)
#pragma unroll
      for (int kx = 0; kx < 3; ++kx)
        pw[ky * 3 + kx] = *reinterpret_cast<const uint4*>(
            &pr_s[((oy + ky) * 18 + ox + kx) * PRS + wv * 8]);
    f32x2 ac0 = {0.f, 0.f}, ac1 = {0.f, 0.f}, ac2 = {0.f, 0.f}, ac3 = {0.f, 0.f};
#pragma unroll
    for (int kk = 0; kk < 9; ++kk) {
      ac0 += dm2[kk][0] * unpk2(pw[kk].x);
      ac1 += dm2[kk][1] * unpk2(pw[kk].y);
      ac2 += dm2[kk][2] * unpk2(pw[kk].z);
      ac3 += dm2[kk][3] * unpk2(pw[kk].w);
    }
    opk[i * 4 + 0] = pk2(ac0.x, ac0.y);
    opk[i * 4 + 1] = pk2(ac1.x, ac1.y);
    opk[i * 4 + 2] = pk2(ac2.x, ac2.y);
    opk[i * 4 + 3] = pk2(ac3.x, ac3.y);
    osq[0] += ac0.x * ac0.x; osq[1] += ac0.y * ac0.y;
    osq[2] += ac1.x * ac1.x; osq[3] += ac1.y * ac1.y;
    osq[4] += ac2.x * ac2.x; osq[5] += ac2.y * ac2.y;
    osq[6] += ac3.x * ac3.x; osq[7] += ac3.y * ac3.y;
  }
}

// ---------------- fused QK+Gram (y=0) / V+res16 (y=1)
__global__ __launch_bounds__(512)
void k_qkgv(const short* __restrict__ xnb, const short* __restrict__ wqkvb,
            const short* __restrict__ wcb,
            const float* __restrict__ dw_q, const float* __restrict__ dw_k,
            const float* __restrict__ dw_v,
            short* __restrict__ aov, short* __restrict__ res16,
            float* __restrict__ Spart, float* __restrict__ Qpart,
            float* __restrict__ Kpart) {
  __shared__ __align__(16) char smem[76800];
  short* pr_s = (short*)smem;                 // 51072 B during phases
  short* qk_s = (short*)smem;                 // 68608 B after phases (q then k)
  float* gram_s = (float*)(smem + 68608);     // 8192 B
  const int tid = threadIdx.x;
  const int lane = tid & 63;
  const int wv = tid >> 6;          // 0..7
  const int olocal = lane & 15;
  const int g = lane >> 4;          // 0..3
  const int tx = blockIdx.x & 15, ty = (blockIdx.x >> 4) & 15, b = blockIdx.x >> 8;
  const int tile = blockIdx.x & 255;
  const int x0 = tx * 16 - 1, y0 = ty * 16 - 1;

  if (blockIdx.y == 0) {
    // ---- QK + per-head Gram path (q,k never hit HBM)
    uint32_t qpk[16], kpk[16];
    float sq[8] = {0.f, 0.f, 0.f, 0.f, 0.f, 0.f, 0.f, 0.f};
    float sk[8] = {0.f, 0.f, 0.f, 0.f, 0.f, 0.f, 0.f, 0.f};
    qk_phase<0>(xnb, wqkvb, dw_q, pr_s, b, x0, y0, lane, wv, olocal, g, qpk, sq);
    __syncthreads();
    qk_phase<1>(xnb, wqkvb, dw_k, pr_s, b, x0, y0, lane, wv, olocal, g, kpk, sk);

    // wave-reduce sumsq (64-lane butterfly), lane 0 writes partials
#pragma unroll
    for (int d = 1; d < 64; d <<= 1) {
#pragma unroll
      for (int u = 0; u < 8; ++u) {
        sq[u] += __shfl_xor(sq[u], d);
        sk[u] += __shfl_xor(sk[u], d);
      }
    }
    if (lane == 0) {
#pragma unroll
      for (int u = 0; u < 8; ++u) {
        Qpart[((size_t)b * 256 + tile) * 64 + wv * 8 + u] = sq[u];
        Kpart[((size_t)b * 256 + tile) * 64 + wv * 8 + u] = sk[u];
      }
    }
    __syncthreads();  // all pr_s reads done; reuse region as qk_s

    // stage q,k tiles into LDS [ch][px] (bank-friendly stride QKS)
#pragma unroll
    for (int i = 0; i < 4; ++i) {
      const int px = lane + i * 64;
#pragma unroll
      for (int u2 = 0; u2 < 4; ++u2) {
        const int ch = wv * 8 + 2 * u2;
        const uint32_t wq = qpk[i * 4 + u2], wk = kpk[i * 4 + u2];
        qk_s[ch * QKS + px] = (short)(wq & 0xffff);
        qk_s[(ch + 1) * QKS + px] = (short)(wq >> 16);
        qk_s[KOFF + ch * QKS + px] = (short)(wk & 0xffff);
        qk_s[KOFF + (ch + 1) * QKS + px] = (short)(wk >> 16);
      }
    }
    __syncthreads();

    // per-head Gram: wave wv -> head wv>>1, px-half wv&1 (4 K-steps of 32)
    const int h = wv >> 1, half = wv & 1;
    f32x4 sacc = {0.f, 0.f, 0.f, 0.f};
#pragma unroll
    for (int c4 = 0; c4 < 4; ++c4) {
      const int chunk = half * 4 + c4;
      const int off = (h * 16 + olocal) * QKS + chunk * 32 + g * 8;
      short8 A = *reinterpret_cast<const short8*>(&qk_s[off]);
      short8 Bf = *reinterpret_cast<const short8*>(&qk_s[KOFF + off]);
      sacc = __builtin_amdgcn_mfma_f32_16x16x32_bf16(A, Bf, sacc, 0, 0, 0);
    }
#pragma unroll
    for (int r = 0; r < 4; ++r)
      gram_s[wv * 256 + (g * 4 + r) * 16 + olocal] = sacc[r];
    __syncthreads();
    if (!(wv & 1)) {
#pragma unroll
      for (int m = 0; m < 4; ++m) {
        const int idx = lane + m * 64;
        Spart[(((size_t)b * 256 + tile) * 4 + h) * 256 + idx] =
            gram_s[wv * 256 + idx] + gram_s[(wv + 1) * 256 + idx];
      }
    }
  } else {
    // ---- V + res16 path (r16-proven code)
    {
      short8 wc0 = *reinterpret_cast<const short8*>(wcb + olocal * 64 + g * 8);
      short8 wc1 = *reinterpret_cast<const short8*>(wcb + olocal * 64 + 32 + g * 8);
#pragma unroll
      for (int t2 = 0; t2 < 2; ++t2) {
        const int oy = wv * 2 + t2;
        const int n = (ty * 16 + oy) * WW + tx * 16 + olocal;
        const short* bb = xnb + ((size_t)b * NPIX + n) * 64 + g * 8;
        short8 b0 = *reinterpret_cast<const short8*>(bb);
        short8 b1 = *reinterpret_cast<const short8*>(bb + 32);
        f32x4 acc = {0.f, 0.f, 0.f, 0.f};
        acc = __builtin_amdgcn_mfma_f32_16x16x32_bf16(wc0, b0, acc, 0, 0, 0);
        acc = __builtin_amdgcn_mfma_f32_16x16x32_bf16(wc1, b1, acc, 0, 0, 0);
        uint2 st;
        st.x = pk2(acc[0], acc[1]);
        st.y = pk2(acc[2], acc[3]);
        *reinterpret_cast<uint2*>(&res16[((size_t)b * NPIX + n) * 16 + g * 4]) = st;
      }
    }
    short8 Bt[4][2];
#pragma unroll
    for (int ot = 0; ot < 4; ++ot) {
      const short* wb = wqkvb + 2 * 4096 + (ot * 16 + olocal) * 64 + g * 8;
      Bt[ot][0] = *reinterpret_cast<const short8*>(wb);
      Bt[ot][1] = *reinterpret_cast<const short8*>(wb + 32);
    }
    short8 a0[3], a1[3];
#pragma unroll
    for (int j = 0; j < 3; ++j) {
      const int pt = wv + j * 8;
      const int p = pt * 16 + olocal;
      const int py = y0 + p / 18;
      const int px_ = x0 + p % 18;
      const bool vld = (pt < 21) && (p < 324) && ((unsigned)py < 256u) && ((unsigned)px_ < 256u);
      if (vld) {
        const short* ab = xnb + ((size_t)b * NPIX + py * WW + px_) * 64 + g * 8;
        a0[j] = *reinterpret_cast<const short8*>(ab);
        a1[j] = *reinterpret_cast<const short8*>(ab + 32);
      } else {
        a0[j] = zero8();
        a1[j] = zero8();
      }
    }
#pragma unroll
    for (int j = 0; j < 3; ++j) {
      const int pt = wv + j * 8;
      if (pt >= 21) continue;
      const int p2 = pt * 16 + olocal;
#pragma unroll
      for (int ot = 0; ot < 4; ++ot) {
        f32x4 acc = {0.f, 0.f, 0.f, 0.f};
        acc = __builtin_amdgcn_mfma_f32_16x16x32_bf16(Bt[ot][0], a0[j], acc, 0, 0, 0);
        acc = __builtin_amdgcn_mfma_f32_16x16x32_bf16(Bt[ot][1], a1[j], acc, 0, 0, 0);
        uint2 st;
        st.x = pk2t(acc[0], acc[1]);
        st.y = pk2t(acc[2], acc[3]);
        *reinterpret_cast<uint2*>(&pr_s[p2 * PRS + ot * 16 + g * 4]) = st;
      }
    }
    __syncthreads();
    f32x2 dm2[9][4];
#pragma unroll
    for (int u2 = 0; u2 < 4; ++u2)
#pragma unroll
      for (int kk = 0; kk < 9; ++kk) {
        dm2[kk][u2].x = dw_v[(wv * 8 + 2 * u2) * 9 + kk];
        dm2[kk][u2].y = dw_v[(wv * 8 + 2 * u2 + 1) * 9 + kk];
      }
#pragma unroll
    for (int i = 0; i < 4; ++i) {
      const int pxl = lane + i * 64;
      const int oy = pxl >> 4, ox = pxl & 15;
      uint4 pw[9];
#pragma unroll
      for (int ky = 0; ky < 3; ++ky)
#pragma unroll
        for (int kx = 0; kx < 3; ++kx)
          pw[ky * 3 + kx] = *reinterpret_cast<const uint4*>(
              &pr_s[((oy + ky) * 18 + ox + kx) * PRS + wv * 8]);
      f32x2 ac0 = {0.f, 0.f}, ac1 = {0.f, 0.f}, ac2 = {0.f, 0.f}, ac3 = {0.f, 0.f};
#pragma unroll
      for (int kk = 0; kk < 9; ++kk) {
        ac0 += dm2[kk][0] * unpk2(pw[kk].x);
        ac1 += dm2[kk][1] * unpk2(pw[kk].y);
        ac2 += dm2[kk][2] * unpk2(pw[kk].z);
        ac3 += dm2[kk][3] * unpk2(pw[kk].w);
      }
      const int n = (ty * 16 + oy) * WW + tx * 16 + ox;
      uint4 st = make_uint4(pk2(ac0.x, ac0.y), pk2(ac1.x, ac1.y),
                            pk2(ac2.x, ac2.y), pk2(ac3.x, ac3.y));
      *reinterpret_cast<uint4*>(&aov[((size_t)b * NPIX + n) * 64 + wv * 8]) = st;
    }
  }
}

// ---------------- reduce 256 per-tile partials, normalize, softmax; emit attb
__global__ __launch_bounds__(256)
void k_softmax(const float* __restrict__ Spart, const float* __restrict__ Qpart,
               const float* __restrict__ Kpart, const float* __restrict__ temp,
               short* __restrict__ attb) {
  const int tid = threadIdx.x;
  const int bh = blockIdx.x;
  const int b = bh >> 2, h = bh & 3;
  const int i = tid >> 4, j = tid & 15;
  float S = 0.f, qs = 0.f, ks = 0.f;
  for (int c = 0; c < 256; ++c) {
    S += Spart[(((size_t)b * 256 + c) * 4 + h) * 256 + tid];
    qs += Qpart[((size_t)b * 256 + c) * 64 + h * 16 + i];
    ks += Kpart[((size_t)b * 256 + c) * 64 + h * 16 + j];
  }
  float nq = fmaxf(sqrtf(qs), 1e-12f);
  float nk = fmaxf(sqrtf(ks), 1e-12f);
  float val = S / (nq * nk) * temp[h];
  float m = val;
  for (int d = 1; d < 16; d <<= 1) m = fmaxf(m, __shfl_xor(m, d));
  float e = __expf(val - m);
  float s = e;
  for (int d = 1; d < 16; d <<= 1) s += __shfl_xor(s, d);
  attb[((size_t)b * 64 + h * 16 + i) * 64 + h * 16 + j] = f2bfs(e / s);
#pragma unroll
  for (int mq = 0; mq < 4; ++mq) {
    const int idx = tid * 4 + mq;
    const int r = idx >> 6, c = idx & 63;
    if ((c >> 4) != h)
      attb[((size_t)b * 64 + h * 16 + r) * 64 + c] = 0;
  }
}

// ---------------- fused: att_out = Attb @ v (block-diag GEMM) -> LDS; conv3x3 + res16
__global__ __launch_bounds__(512)
void k_attf(const short* __restrict__ attb, const short* __restrict__ vao,
            const short* __restrict__ wcpb, const short* __restrict__ res16,
            float* __restrict__ out) {
  __shared__ short ao_s[336 * PRS];
  const int tid = threadIdx.x;
  const int lane = tid & 63;
  const int wv = tid >> 6;
  const int olocal = lane & 15;
  const int g = lane >> 4;
  const int tx = blockIdx.x & 15, ty = (blockIdx.x >> 4) & 15, b = blockIdx.x >> 8;
  const int x0 = tx * 16 - 1, y0 = ty * 16 - 1;

  {
    short8 AT[4][2];
#pragma unroll
    for (int ot = 0; ot < 4; ++ot) {
      const short* ab = attb + ((size_t)b * 64 + ot * 16 + olocal) * 64 + g * 8;
      AT[ot][0] = *reinterpret_cast<const short8*>(ab);
      AT[ot][1] = *reinterpret_cast<const short8*>(ab + 32);
    }
#pragma unroll
    for (int j = 0; j < 3; ++j) {
      const int pt = wv + j * 8;
      if (pt >= 21) continue;
      const int p = pt * 16 + olocal;
      const int py = y0 + p / 18;
      const int px_ = x0 + p % 18;
      const bool vld = (p < 324) && ((unsigned)py < 256u) && ((unsigned)px_ < 256u);
      short8 b0 = zero8(), b1 = zero8();
      if (vld) {
        const short* vp = vao + ((size_t)b * NPIX + py * WW + px_) * 64 + g * 8;
        b0 = *reinterpret_cast<const short8*>(vp);
        b1 = *reinterpret_cast<const short8*>(vp + 32);
      }
#pragma unroll
      for (int ot = 0; ot < 4; ++ot) {
        f32x4 acc = {0.f, 0.f, 0.f, 0.f};
        acc = __builtin_amdgcn_mfma_f32_16x16x32_bf16(AT[ot][0], b0, acc, 0, 0, 0);
        acc = __builtin_amdgcn_mfma_f32_16x16x32_bf16(AT[ot][1], b1, acc, 0, 0, 0);
        uint2 st;
        st.x = pk2t(acc[0], acc[1]);
        st.y = pk2t(acc[2], acc[3]);
        *reinterpret_cast<uint2*>(&ao_s[p * PRS + ot * 16 + g * 4]) = st;
      }
    }
  }
  __syncthreads();

  short8 WA[9][2];
#pragma unroll
  for (int kk = 0; kk < 9; ++kk) {
    const short* wb = wcpb + (kk * 16 + olocal) * 64 + g * 8;
    WA[kk][0] = *reinterpret_cast<const short8*>(wb);
    WA[kk][1] = *reinterpret_cast<const short8*>(wb + 32);
  }
#pragma unroll
  for (int s = 0; s < 2; ++s) {
    const int oy = wv * 2 + s;
    const int n0 = (ty * 16 + oy) * WW + tx * 16;
    uint2 rv = *reinterpret_cast<const uint2*>(
        &res16[((size_t)b * NPIX + n0 + olocal) * 16 + g * 4]);
    f32x4 acc;
    acc[0] = __uint_as_float(rv.x << 16);
    acc[1] = __uint_as_float(rv.x & 0xffff0000u);
    acc[2] = __uint_as_float(rv.y << 16);
    acc[3] = __uint_as_float(rv.y & 0xffff0000u);
#pragma unroll
    for (int ky = 0; ky < 3; ++ky)
#pragma unroll
      for (int kx = 0; kx < 3; ++kx) {
        const int hp = (oy + ky) * 18 + olocal + kx;
        short8 b0 = *reinterpret_cast<const short8*>(&ao_s[hp * PRS + g * 8]);
        short8 b1 = *reinterpret_cast<const short8*>(&ao_s[hp * PRS + 32 + g * 8]);
        acc = __builtin_amdgcn_mfma_f32_16x16x32_bf16(WA[ky * 3 + kx][0], b0, acc, 0, 0, 0);
        acc = __builtin_amdgcn_mfma_f32_16x16x32_bf16(WA[ky * 3 + kx][1], b1, acc, 0, 0, 0);
      }
    float* op = out + ((size_t)b * 16 + g * 4) * NPIX + n0 + olocal;
    op[0] = acc[0];
    op[NPIX] = acc[1];
    op[2 * NPIX] = acc[2];
    op[3 * NPIX] = acc[3];
  }
}

extern "C" void kernel_launch(void* const* d_in, const int* in_sizes, int n_in,
                              void* d_out, int out_size, void* d_ws, size_t ws_size,
                              hipStream_t stream) {
  const float* x      = (const float*)d_in[0];
  const float* ln_w   = (const float*)d_in[1];
  const float* ln_b   = (const float*)d_in[2];
  const float* w_q    = (const float*)d_in[3];
  const float* w_k    = (const float*)d_in[4];
  const float* w_v    = (const float*)d_in[5];
  const float* dw_q   = (const float*)d_in[6];
  const float* dw_k   = (const float*)d_in[7];
  const float* dw_v   = (const float*)d_in[8];
  const float* w_proj = (const float*)d_in[9];
  const float* w_comp = (const float*)d_in[10];
  const float* temp   = (const float*)d_in[11];
  float* out = (float*)d_out;

  const size_t SPX = (size_t)BB * NPIX;
  short* xnb   = (short*)d_ws;                 // 67 MB pixel-major LN'd x
  short* aov   = xnb + SPX * 64;               // 67 MB pixel-major v / att_out
  short* res16 = aov + SPX * 64;               // 16 MB
  short* wcpb  = res16 + SPX * 16;             // 9216
  short* wqkvb = wcpb + 9216;                  // 12288
  short* wcb   = wqkvb + 12288;                // 1024
  short* attb  = wcb + 1024;                   // 32768
  float* Spart = (float*)(attb + 32768 + 512); // 8*256*4*256 f32 (8 MB)
  float* Qpart = Spart + (size_t)8 * 256 * 4 * 256;
  float* Kpart = Qpart + (size_t)8 * 256 * 64;

  k_prep<<<52, 256, 0, stream>>>(w_comp, w_proj, w_q, w_k, w_v, wcpb, wqkvb, wcb);
  k_ln<<<2048, 256, 0, stream>>>(x, ln_w, ln_b, xnb);
  dim3 gqk(2048, 2);
  k_qkgv<<<gqk, 512, 0, stream>>>(xnb, wqkvb, wcb, dw_q, dw_k, dw_v,
                                  aov, res16, Spart, Qpart, Kpart);
  k_softmax<<<32, 256, 0, stream>>>(Spart, Qpart, Kpart, temp, attb);
  k_attf<<<2048, 512, 0, stream>>>(attb, aov, wcpb, res16, out);
}

// Round 18
// 309.880 us; speedup vs baseline: 1.7277x; 1.7277x over previous
//
#include <hip/hip_runtime.h>
#include <hip/hip_bf16.h>
#include <stdint.h>

#define BB 8
#define CC 64
#define HH 256
#define WW 256
#define NPIX 65536
#define HEADS 4
#define HD 16
#define PRS 76  // LDS row stride in shorts (152 B -> conflict-free b128 reads, verified r6)

using bf16 = __hip_bfloat16;
typedef __attribute__((ext_vector_type(8))) short short8;
typedef __attribute__((ext_vector_type(4))) float f32x4;
typedef __attribute__((ext_vector_type(2))) float f32x2;

__device__ __forceinline__ float bf2f(bf16 v) { return __bfloat162float(v); }
__device__ __forceinline__ bf16 f2bf(float v) { return __float2bfloat16(v); }
__device__ __forceinline__ short f2bfs(float f) { bf16 h = __float2bfloat16(f); return *reinterpret_cast<short*>(&h); }
__device__ __forceinline__ float bfs2f(short s) { return __uint_as_float(((uint32_t)(uint16_t)s) << 16); }
__device__ __forceinline__ uint32_t pk2(float a, float b) {
  return (uint32_t)(uint16_t)f2bfs(a) | ((uint32_t)(uint16_t)f2bfs(b) << 16);
}
// truncating bf16 pack (LDS intermediates only; RNE kept for final tensors)
__device__ __forceinline__ uint32_t pk2t(float a, float b) {
  return (__float_as_uint(a) >> 16) | (__float_as_uint(b) & 0xffff0000u);
}
__device__ __forceinline__ short8 zero8() { short8 z = {0, 0, 0, 0, 0, 0, 0, 0}; return z; }
__device__ __forceinline__ f32x2 unpk2(uint32_t w) {
  f32x2 r;
  r.x = __uint_as_float(w << 16);
  r.y = __uint_as_float(w & 0xffff0000u);
  return r;
}

// ---------------- prep: wcpb = w_comp*w_proj folded (bf16); wqkvb, wcb = bf16 weights
__global__ void k_prep(const float* __restrict__ w_comp, const float* __restrict__ w_proj,
                       const float* __restrict__ w_q, const float* __restrict__ w_k,
                       const float* __restrict__ w_v,
                       short* __restrict__ wcpb, short* __restrict__ wqkvb,
                       short* __restrict__ wcb) {
  int idx = blockIdx.x * 256 + threadIdx.x;
  if (idx < 9 * 16 * 64) {
    int c = idx & 63;
    int o = (idx >> 6) & 15;
    int kk = idx >> 10;
    float acc = 0.f;
    for (int m = 0; m < 64; ++m)
      acc += w_comp[o * 64 + m] * w_proj[(m * 64 + c) * 9 + kk];
    wcpb[idx] = f2bfs(acc);
  }
  if (idx < 3 * 4096) {
    const float* Ws[3] = {w_q, w_k, w_v};
    wqkvb[idx] = f2bfs(Ws[idx >> 12][idx & 4095]);
  }
  if (idx < 1024) wcb[idx] = f2bfs(w_comp[idx]);
}

// ---------------- LayerNorm: x (channel-major fp32) -> xn (pixel-major bf16)
__global__ __launch_bounds__(256)
void k_ln(const float* __restrict__ x, const float* __restrict__ ln_w,
          const float* __restrict__ ln_b, short* __restrict__ xnb) {
  const int tid = threadIdx.x;
  const int b = blockIdx.x >> 8;
  const int n = ((blockIdx.x & 255) << 8) + tid;
  const float* xp = x + (size_t)b * CC * NPIX + n;
  float v[64];
  float s = 0.f, s2 = 0.f;
#pragma unroll
  for (int c = 0; c < 64; ++c) {
    float t0 = xp[(size_t)c * NPIX];
    v[c] = t0; s += t0; s2 += t0 * t0;
  }
  const float mu = s * (1.f / 64.f);
  const float r = rsqrtf(s2 * (1.f / 64.f) - mu * mu + 1e-6f);
  short* op = xnb + ((size_t)b * NPIX + n) * 64;
#pragma unroll
  for (int c8 = 0; c8 < 8; ++c8) {
    uint32_t pk[4];
#pragma unroll
    for (int j = 0; j < 4; ++j) {
      const int c0 = c8 * 8 + 2 * j;
      float f0 = (v[c0] - mu) * r * ln_w[c0] + ln_b[c0];
      float f1 = (v[c0 + 1] - mu) * r * ln_w[c0 + 1] + ln_b[c0 + 1];
      pk[j] = pk2(f0, f1);
    }
    *reinterpret_cast<uint4*>(op + c8 * 8) = make_uint4(pk[0], pk[1], pk[2], pk[3]);
  }
}

// ---------------- QKV (t = blockIdx.y): 1x1 MFMA + depthwise 3x3 (r11 shape, batched taps)
__global__ __launch_bounds__(512)
void k_qkv(const short* __restrict__ xnb, const short* __restrict__ wqkvb,
           const short* __restrict__ wcb,
           const float* __restrict__ dw_q, const float* __restrict__ dw_k,
           const float* __restrict__ dw_v,
           bf16* __restrict__ qo, bf16* __restrict__ ko,
           short* __restrict__ aov, short* __restrict__ res16) {
  __shared__ short pr_s[336 * PRS];  // 1x1 output tile, [halo pix][64 outch]
  const int tid = threadIdx.x;
  const int lane = tid & 63;
  const int wv = tid >> 6;          // wave 0..7
  const int olocal = lane & 15;
  const int g = lane >> 4;          // 0..3
  const int t = blockIdx.y;         // 0=q, 1=k, 2=v
  const int tx = blockIdx.x & 15, ty = (blockIdx.x >> 4) & 15, b = blockIdx.x >> 8;
  const int x0 = tx * 16 - 1, y0 = ty * 16 - 1;

  // res16[b][n][o16] = w_comp @ xn (center pixels) — only in the t==0 slice
  if (t == 0) {
    short8 wc0 = *reinterpret_cast<const short8*>(wcb + olocal * 64 + g * 8);
    short8 wc1 = *reinterpret_cast<const short8*>(wcb + olocal * 64 + 32 + g * 8);
#pragma unroll
    for (int t2 = 0; t2 < 2; ++t2) {
      const int oy = wv * 2 + t2;  // 0..15
      const int n = (ty * 16 + oy) * WW + tx * 16 + olocal;
      const short* bb = xnb + ((size_t)b * NPIX + n) * 64 + g * 8;
      short8 b0 = *reinterpret_cast<const short8*>(bb);
      short8 b1 = *reinterpret_cast<const short8*>(bb + 32);
      f32x4 acc = {0.f, 0.f, 0.f, 0.f};
      acc = __builtin_amdgcn_mfma_f32_16x16x32_bf16(wc0, b0, acc, 0, 0, 0);
      acc = __builtin_amdgcn_mfma_f32_16x16x32_bf16(wc1, b1, acc, 0, 0, 0);
      uint2 st;
      st.x = pk2(acc[0], acc[1]);
      st.y = pk2(acc[2], acc[3]);
      *reinterpret_cast<uint2*>(&res16[((size_t)b * NPIX + n) * 16 + g * 4]) = st;
    }
  }

  // weight frags for 1x1 (L2-hot)
  short8 Bt[4][2];
#pragma unroll
  for (int ot = 0; ot < 4; ++ot) {
    const short* wb = wqkvb + t * 4096 + (ot * 16 + olocal) * 64 + g * 8;
    Bt[ot][0] = *reinterpret_cast<const short8*>(wb);
    Bt[ot][1] = *reinterpret_cast<const short8*>(wb + 32);
  }

  // phase2: 1x1 projection via MFMA, A=weights B=xn -> D[ch][px]; packed b64 LDS writes
  short8 a0[3], a1[3];
#pragma unroll
  for (int j = 0; j < 3; ++j) {
    const int pt = wv + j * 8;
    const int p = pt * 16 + olocal;
    const int py = y0 + p / 18;
    const int px_ = x0 + p % 18;
    const bool vld = (pt < 21) && (p < 324) && ((unsigned)py < 256u) && ((unsigned)px_ < 256u);
    if (vld) {
      const short* ab = xnb + ((size_t)b * NPIX + py * WW + px_) * 64 + g * 8;
      a0[j] = *reinterpret_cast<const short8*>(ab);
      a1[j] = *reinterpret_cast<const short8*>(ab + 32);
    } else {
      a0[j] = zero8();
      a1[j] = zero8();
    }
  }
#pragma unroll
  for (int j = 0; j < 3; ++j) {
    const int pt = wv + j * 8;
    if (pt >= 21) continue;
    const int p2 = pt * 16 + olocal;   // this lane's pixel (D col = olocal)
#pragma unroll
    for (int ot = 0; ot < 4; ++ot) {
      f32x4 acc = {0.f, 0.f, 0.f, 0.f};
      acc = __builtin_amdgcn_mfma_f32_16x16x32_bf16(Bt[ot][0], a0[j], acc, 0, 0, 0);
      acc = __builtin_amdgcn_mfma_f32_16x16x32_bf16(Bt[ot][1], a1[j], acc, 0, 0, 0);
      uint2 st;
      st.x = pk2t(acc[0], acc[1]);
      st.y = pk2t(acc[2], acc[3]);
      *reinterpret_cast<uint2*>(&pr_s[p2 * PRS + ot * 16 + g * 4]) = st;
    }
  }
  __syncthreads();

  // phase3: depthwise 3x3; BATCHED tap loads (9 independent b128 reads in flight)
  const float* dmt = (t == 0) ? dw_q : (t == 1) ? dw_k : dw_v;
  f32x2 dm2[9][4];
#pragma unroll
  for (int u2 = 0; u2 < 4; ++u2)
#pragma unroll
    for (int kk = 0; kk < 9; ++kk) {
      dm2[kk][u2].x = dmt[(wv * 8 + 2 * u2) * 9 + kk];
      dm2[kk][u2].y = dmt[(wv * 8 + 2 * u2 + 1) * 9 + kk];
    }
  bf16* ob = ((t == 0) ? qo : ko) + (size_t)b * CC * NPIX;
#pragma unroll
  for (int i = 0; i < 4; ++i) {
    const int pxl = lane + i * 64;
    const int oy = pxl >> 4, ox = pxl & 15;
    uint4 pw[9];
#pragma unroll
    for (int ky = 0; ky < 3; ++ky)
#pragma unroll
      for (int kx = 0; kx < 3; ++kx)
        pw[ky * 3 + kx] = *reinterpret_cast<const uint4*>(
            &pr_s[((oy + ky) * 18 + ox + kx) * PRS + wv * 8]);
    f32x2 ac0 = {0.f, 0.f}, ac1 = {0.f, 0.f}, ac2 = {0.f, 0.f}, ac3 = {0.f, 0.f};
#pragma unroll
    for (int kk = 0; kk < 9; ++kk) {
      ac0 += dm2[kk][0] * unpk2(pw[kk].x);
      ac1 += dm2[kk][1] * unpk2(pw[kk].y);
      ac2 += dm2[kk][2] * unpk2(pw[kk].z);
      ac3 += dm2[kk][3] * unpk2(pw[kk].w);
    }
    const int n = (ty * 16 + oy) * WW + tx * 16 + ox;
    if (t < 2) {
      ob[(size_t)(wv * 8 + 0) * NPIX + n] = f2bf(ac0.x);
      ob[(size_t)(wv * 8 + 1) * NPIX + n] = f2bf(ac0.y);
      ob[(size_t)(wv * 8 + 2) * NPIX + n] = f2bf(ac1.x);
      ob[(size_t)(wv * 8 + 3) * NPIX + n] = f2bf(ac1.y);
      ob[(size_t)(wv * 8 + 4) * NPIX + n] = f2bf(ac2.x);
      ob[(size_t)(wv * 8 + 5) * NPIX + n] = f2bf(ac2.y);
      ob[(size_t)(wv * 8 + 6) * NPIX + n] = f2bf(ac3.x);
      ob[(size_t)(wv * 8 + 7) * NPIX + n] = f2bf(ac3.y);
    } else {
      uint4 st = make_uint4(pk2(ac0.x, ac0.y), pk2(ac1.x, ac1.y),
                            pk2(ac2.x, ac2.y), pk2(ac3.x, ac3.y));
      *reinterpret_cast<uint4*>(&aov[((size_t)b * NPIX + n) * 64 + wv * 8]) = st;
    }
  }
}

// ---------------- partial logits + sumsq via MFMA; 32 chunks/bh, 16 K-steps/wave
__global__ __launch_bounds__(256)
void k_logits(const bf16* __restrict__ q, const bf16* __restrict__ kk_,
              float* __restrict__ Spart, float* __restrict__ Qpart,
              float* __restrict__ Kpart) {
  const int tid = threadIdx.x;
  const int lane = tid & 63;
  const int wv = tid >> 6;            // 0..3
  const int bh = blockIdx.x >> 5;     // 0..31
  const int chunk = blockIdx.x & 31;  // 0..31
  const int row = lane & 15;
  const int g = lane >> 4;
  const short* qp = (const short*)q + (size_t)(bh * HD + row) * NPIX;
  const short* kp = (const short*)kk_ + (size_t)(bh * HD + row) * NPIX;
  const int n0 = chunk * 2048 + wv * 512 + g * 8;
  f32x4 s = {0.f, 0.f, 0.f, 0.f};
  f32x4 sq = {0.f, 0.f, 0.f, 0.f};
  f32x4 sk = {0.f, 0.f, 0.f, 0.f};
#pragma unroll
  for (int it = 0; it < 16; ++it) {
    const int n = n0 + it * 32;
    short8 qa = *reinterpret_cast<const short8*>(qp + n);
    short8 ka = *reinterpret_cast<const short8*>(kp + n);
    s  = __builtin_amdgcn_mfma_f32_16x16x32_bf16(qa, ka, s, 0, 0, 0);
    sq = __builtin_amdgcn_mfma_f32_16x16x32_bf16(qa, qa, sq, 0, 0, 0);
    sk = __builtin_amdgcn_mfma_f32_16x16x32_bf16(ka, ka, sk, 0, 0, 0);
  }
  const size_t tile = (size_t)blockIdx.x * 4 + wv;
  float* sp = Spart + tile * 256;
#pragma unroll
  for (int r = 0; r < 4; ++r)
    sp[(g * 4 + r) * 16 + row] = s[r];
  if ((row >> 2) == g) {
    Qpart[tile * 16 + row] = sq[row & 3];
    Kpart[tile * 16 + row] = sk[row & 3];
  }
}

// ---------------- reduce partials (128 tiles/bh), normalize, softmax; emit attb
__global__ __launch_bounds__(256)
void k_softmax(const float* __restrict__ Spart, const float* __restrict__ Qpart,
               const float* __restrict__ Kpart, const float* __restrict__ temp,
               short* __restrict__ attb) {
  const int tid = threadIdx.x;
  const int bh = blockIdx.x;
  const int b = bh >> 2, h = bh & 3;
  const int i = tid >> 4, j = tid & 15;
  float S = 0.f, qs = 0.f, ks = 0.f;
  const size_t t0 = (size_t)bh * 128;
  for (int c = 0; c < 128; ++c) {
    S += Spart[(t0 + c) * 256 + tid];
    qs += Qpart[(t0 + c) * 16 + i];
    ks += Kpart[(t0 + c) * 16 + j];
  }
  float nq = fmaxf(sqrtf(qs), 1e-12f);
  float nk = fmaxf(sqrtf(ks), 1e-12f);
  float val = S / (nq * nk) * temp[h];
  float m = val;
  for (int d = 1; d < 16; d <<= 1) m = fmaxf(m, __shfl_xor(m, d));
  float e = __expf(val - m);
  float s = e;
  for (int d = 1; d < 16; d <<= 1) s += __shfl_xor(s, d);
  attb[((size_t)b * 64 + h * 16 + i) * 64 + h * 16 + j] = f2bfs(e / s);
#pragma unroll
  for (int mq = 0; mq < 4; ++mq) {
    const int idx = tid * 4 + mq;          // 0..1023
    const int r = idx >> 6, c = idx & 63;
    if ((c >> 4) != h)
      attb[((size_t)b * 64 + h * 16 + r) * 64 + c] = 0;
  }
}

// ---------------- fused: att_out = Attb @ v (block-diag GEMM) -> LDS; conv3x3 + res16
__global__ __launch_bounds__(512)
void k_attf(const short* __restrict__ attb, const short* __restrict__ vao,
            const short* __restrict__ wcpb, const short* __restrict__ res16,
            float* __restrict__ out) {
  __shared__ short ao_s[336 * PRS];  // att_out halo tile, [halo pix][64ch]
  const int tid = threadIdx.x;
  const int lane = tid & 63;
  const int wv = tid >> 6;          // 0..7
  const int olocal = lane & 15;
  const int g = lane >> 4;
  const int tx = blockIdx.x & 15, ty = (blockIdx.x >> 4) & 15, b = blockIdx.x >> 8;
  const int x0 = tx * 16 - 1, y0 = ty * 16 - 1;

  // phase A: att_out for 324 halo pixels via MFMA (A=attb rows, B=v pixel-major)
  {
    short8 AT[4][2];
#pragma unroll
    for (int ot = 0; ot < 4; ++ot) {
      const short* ab = attb + ((size_t)b * 64 + ot * 16 + olocal) * 64 + g * 8;
      AT[ot][0] = *reinterpret_cast<const short8*>(ab);
      AT[ot][1] = *reinterpret_cast<const short8*>(ab + 32);
    }
#pragma unroll
    for (int j = 0; j < 3; ++j) {
      const int pt = wv + j * 8;
      if (pt >= 21) continue;
      const int p = pt * 16 + olocal;
      const int py = y0 + p / 18;
      const int px_ = x0 + p % 18;
      const bool vld = (p < 324) && ((unsigned)py < 256u) && ((unsigned)px_ < 256u);
      short8 b0 = zero8(), b1 = zero8();
      if (vld) {
        const short* vp = vao + ((size_t)b * NPIX + py * WW + px_) * 64 + g * 8;
        b0 = *reinterpret_cast<const short8*>(vp);
        b1 = *reinterpret_cast<const short8*>(vp + 32);
      }
#pragma unroll
      for (int ot = 0; ot < 4; ++ot) {
        f32x4 acc = {0.f, 0.f, 0.f, 0.f};
        acc = __builtin_amdgcn_mfma_f32_16x16x32_bf16(AT[ot][0], b0, acc, 0, 0, 0);
        acc = __builtin_amdgcn_mfma_f32_16x16x32_bf16(AT[ot][1], b1, acc, 0, 0, 0);
        uint2 st;
        st.x = pk2t(acc[0], acc[1]);
        st.y = pk2t(acc[2], acc[3]);
        *reinterpret_cast<uint2*>(&ao_s[p * PRS + ot * 16 + g * 4]) = st;
      }
    }
  }
  __syncthreads();

  // phase B: conv3x3 via MFMA (A=wcp taps, B=att_out halo from LDS) + res16 seed
  short8 WA[9][2];
#pragma unroll
  for (int kk = 0; kk < 9; ++kk) {
    const short* wb = wcpb + (kk * 16 + olocal) * 64 + g * 8;
    WA[kk][0] = *reinterpret_cast<const short8*>(wb);
    WA[kk][1] = *reinterpret_cast<const short8*>(wb + 32);
  }
#pragma unroll
  for (int s = 0; s < 2; ++s) {
    const int oy = wv * 2 + s;      // 0..15
    const int n0 = (ty * 16 + oy) * WW + tx * 16;
    uint2 rv = *reinterpret_cast<const uint2*>(
        &res16[((size_t)b * NPIX + n0 + olocal) * 16 + g * 4]);
    f32x4 acc;
    acc[0] = __uint_as_float(rv.x << 16);
    acc[1] = __uint_as_float(rv.x & 0xffff0000u);
    acc[2] = __uint_as_float(rv.y << 16);
    acc[3] = __uint_as_float(rv.y & 0xffff0000u);
#pragma unroll
    for (int ky = 0; ky < 3; ++ky)
#pragma unroll
      for (int kx = 0; kx < 3; ++kx) {
        const int hp = (oy + ky) * 18 + olocal + kx;
        short8 b0 = *reinterpret_cast<const short8*>(&ao_s[hp * PRS + g * 8]);
        short8 b1 = *reinterpret_cast<const short8*>(&ao_s[hp * PRS + 32 + g * 8]);
        acc = __builtin_amdgcn_mfma_f32_16x16x32_bf16(WA[ky * 3 + kx][0], b0, acc, 0, 0, 0);
        acc = __builtin_amdgcn_mfma_f32_16x16x32_bf16(WA[ky * 3 + kx][1], b1, acc, 0, 0, 0);
      }
    float* op = out + ((size_t)b * 16 + g * 4) * NPIX + n0 + olocal;
    op[0] = acc[0];
    op[NPIX] = acc[1];
    op[2 * NPIX] = acc[2];
    op[3 * NPIX] = acc[3];
  }
}

extern "C" void kernel_launch(void* const* d_in, const int* in_sizes, int n_in,
                              void* d_out, int out_size, void* d_ws, size_t ws_size,
                              hipStream_t stream) {
  const float* x      = (const float*)d_in[0];
  const float* ln_w   = (const float*)d_in[1];
  const float* ln_b   = (const float*)d_in[2];
  const float* w_q    = (const float*)d_in[3];
  const float* w_k    = (const float*)d_in[4];
  const float* w_v    = (const float*)d_in[5];
  const float* dw_q   = (const float*)d_in[6];
  const float* dw_k   = (const float*)d_in[7];
  const float* dw_v   = (const float*)d_in[8];
  const float* w_proj = (const float*)d_in[9];
  const float* w_comp = (const float*)d_in[10];
  const float* temp   = (const float*)d_in[11];
  float* out = (float*)d_out;

  const size_t SPX = (size_t)BB * NPIX;   // 524288 pixels
  short* xnb   = (short*)d_ws;            // SPX*64  (67 MB) pixel-major LN'd x
  short* qb    = xnb + SPX * 64;          // planar bf16 q
  short* kb    = qb + SPX * 64;           // planar bf16 k
  short* aov   = kb + SPX * 64;           // pixel-major v
  short* res16 = aov + SPX * 64;          // SPX*16 (16 MB)
  short* wcpb  = res16 + SPX * 16;        // 9216
  short* wqkvb = wcpb + 9216;             // 12288
  short* wcb   = wqkvb + 12288;           // 1024
  short* attb  = wcb + 1024;              // 8*64*64 bf16 block-diag attn
  float* Spart = (float*)(attb + 8 * 64 * 64 + 512);  // 4096*256 f32 (4 MB)
  float* Qpart = Spart + 4096 * 256;
  float* Kpart = Qpart + 4096 * 16;

  k_prep<<<52, 256, 0, stream>>>(w_comp, w_proj, w_q, w_k, w_v, wcpb, wqkvb, wcb);
  k_ln<<<2048, 256, 0, stream>>>(x, ln_w, ln_b, xnb);
  dim3 gqkv(2048, 3);
  k_qkv<<<gqkv, 512, 0, stream>>>(xnb, wqkvb, wcb, dw_q, dw_k, dw_v,
                                  (bf16*)qb, (bf16*)kb, aov, res16);
  k_logits<<<1024, 256, 0, stream>>>((const bf16*)qb, (const bf16*)kb, Spart, Qpart, Kpart);
  k_softmax<<<32, 256, 0, stream>>>(Spart, Qpart, Kpart, temp, attb);
  k_attf<<<2048, 512, 0, stream>>>(attb, aov, wcpb, res16, out);
}